// Round 7
// baseline (330.659 us; speedup 1.0000x reference)
//
#include <hip/hip_runtime.h>
#include <hip/hip_bf16.h>

#define NS 512
#define NV 32000
#define NB 16
#define NT 128

#ifndef __has_builtin
#define __has_builtin(x) 0
#endif

typedef int v8i __attribute__((ext_vector_type(8)));
typedef float v4f __attribute__((ext_vector_type(4)));

// ---------------------------------------------------------------------------
// e4m3fn (OCP) encode, x >= 0.
// ---------------------------------------------------------------------------
__device__ inline unsigned enc_e4m3(float x) {
    x = fminf(x, 448.0f);
    unsigned u = __float_as_uint(x);
    if (x < 0.015625f) {
        return (unsigned)(int)rintf(x * 512.0f);
    }
    unsigned u2 = u + 0x7FFFFu + ((u >> 20) & 1u);
    return (((u2 >> 23) - 120u) << 3) | ((u2 >> 20) & 7u);
}

__device__ inline unsigned pack4_e4m3(float a, float b, float c, float d) {
#if __has_builtin(__builtin_amdgcn_cvt_pk_fp8_f32)
    int v = __builtin_amdgcn_cvt_pk_fp8_f32(a, b, 0, false);
    v = __builtin_amdgcn_cvt_pk_fp8_f32(c, d, v, true);
    return (unsigned)v;
#else
    return enc_e4m3(a) | (enc_e4m3(b) << 8) | (enc_e4m3(c) << 16) | (enc_e4m3(d) << 24);
#endif
}

// DPP all-lane butterfly reduce within each row of 16 lanes.
#define DPPMAX(x, ctrl) \
    x = fmaxf(x, __int_as_float(__builtin_amdgcn_mov_dpp(__float_as_int(x), ctrl, 0xF, 0xF, true)))
#define DPPADD(x, ctrl) \
    x = x + __int_as_float(__builtin_amdgcn_mov_dpp(__float_as_int(x), ctrl, 0xF, 0xF, true))

// ---------------------------------------------------------------------------
// S1: blocks 0..511  -> scaleZ[s] = 2^-18 / sum_v exp(em[s][v])   (pure stream,
//                       also warms the 64 MB em array into L3)
//     blocks 512..1023 -> zscale[k] = 1024 / sum_d exp(tm[k][d])
// ---------------------------------------------------------------------------
__global__ __launch_bounds__(256) void k_setup1(
    const float* __restrict__ em, const float* __restrict__ tm,
    float* __restrict__ scaleZ, float* __restrict__ zscale)
{
    const int b   = blockIdx.x;
    const int tid = threadIdx.x;
    __shared__ float red[4];

    if (b < NS) {
        const float* row = em + (size_t)b * NV;
        float sum = 0.f;
        const float4* row4 = (const float4*)row;
#pragma unroll 4
        for (int i = 0; i < 31; ++i) {
            float4 v = row4[tid + 256 * i];
            sum += __expf(v.x) + __expf(v.y) + __expf(v.z) + __expf(v.w);
        }
        sum += __expf(row[31744 + tid]);
#pragma unroll
        for (int off = 32; off; off >>= 1) sum += __shfl_down(sum, off);
        if ((tid & 63) == 0) red[tid >> 6] = sum;
        __syncthreads();
        if (tid == 0) scaleZ[b] = 0x1p-18f / ((red[0] + red[1]) + (red[2] + red[3]));
    } else {
        const int k = b - NS;
        const float* row = tm + (size_t)k * NS;
        float2 v = ((const float2*)row)[tid];
        float sum = __expf(v.x) + __expf(v.y);
#pragma unroll
        for (int off = 32; off; off >>= 1) sum += __shfl_down(sum, off);
        if ((tid & 63) == 0) red[tid >> 6] = sum;
        __syncthreads();
        if (tid == 0) zscale[k] = 1024.0f / ((red[0] + red[1]) + (red[2] + red[3]));
    }
}

// ---------------------------------------------------------------------------
// S2: blocks 0..1023  -> fused gather+transpose (em is L3-warm from S1):
//       em_lin[j][s] = exp(em[s][ids[j]]) * scaleZ[s],  32x32 tiles.
//     blocks 1024..1087 -> PT[d][k] = exp(tm[k][d]) * zscale[k] as e4m3 fp8,
//       64x64 LDS-transposed tiles, coalesced uint4 stores.
// ---------------------------------------------------------------------------
__global__ __launch_bounds__(256) void k_setup2(
    const float* __restrict__ em, const float* __restrict__ tm,
    const int* __restrict__ ids, const float* __restrict__ scaleZ,
    const float* __restrict__ zscale, float* __restrict__ em_lin,
    unsigned char* __restrict__ PT)
{
    const int b   = blockIdx.x;
    const int tid = threadIdx.x;
    __shared__ float tile[32][33];
    __shared__ float tile2[64][65];
    __shared__ float zs[64];

    if (b < 1024) {
        const int jb = (b & 63) * 32;
        const int sb = (b >> 6) * 32;
        const int cc = tid & 31;
        const int rr = tid >> 5;
        const int tok = ids[jb + cc];
#pragma unroll
        for (int i = 0; i < 4; ++i) {
            int s = sb + rr + 8 * i;
            tile[rr + 8 * i][cc] = __expf(em[(size_t)s * NV + tok]) * scaleZ[s];
        }
        __syncthreads();
#pragma unroll
        for (int i = 0; i < 4; ++i) {
            int r = rr + 8 * i;
            em_lin[(size_t)(jb + r) * NS + sb + cc] = tile[cc][r];
        }
    } else {
        const int pb = b - 1024;
        const int kb = (pb & 7) * 64;
        const int db = (pb >> 3) * 64;
        const int c  = tid & 63;
        const int r0 = tid >> 6;
        if (tid < 64) zs[tid] = zscale[kb + tid];
#pragma unroll
        for (int i = 0; i < 16; ++i) {
            int r = r0 + 4 * i;
            tile2[r][c] = tm[(size_t)(kb + r) * NS + db + c];
        }
        __syncthreads();
        const int d  = tid >> 2;
        const int ks = (tid & 3) * 16;
        unsigned px[4];
#pragma unroll
        for (int gq = 0; gq < 4; ++gq) {
            int k0 = ks + gq * 4;
            px[gq] = pack4_e4m3(__expf(tile2[k0 + 0][d]) * zs[k0 + 0],
                                __expf(tile2[k0 + 1][d]) * zs[k0 + 1],
                                __expf(tile2[k0 + 2][d]) * zs[k0 + 2],
                                __expf(tile2[k0 + 3][d]) * zs[k0 + 3]);
        }
        uint4 o; o.x = px[0]; o.y = px[1]; o.z = px[2]; o.w = px[3];
        *(uint4*)(PT + (size_t)(db + d) * NS + kb + ks) = o;
    }
}

// ---------------------------------------------------------------------------
// K3 v5 (consumer-quantize): 4 blocks x 4 batches, 8 waves.
//   Per step: [epf prefetch] -> quantize prev av (per-wave max DPP, one
//   float4 LDS exchange, pack + 4x4 DPP byte transpose, Ew write) -> barrier
//   -> A-read -> 16 MFMA -> av = C * epf.  Two barriers, no alpha round-trip.
//   Ew rows 4..15 zeroed once (phantom M-rows); row stride 528 B (bank pad).
//   Numerics identical to r6 (global per-batch pow2 scale, gsum init 18).
// ---------------------------------------------------------------------------
__global__ __launch_bounds__(512, 1) void k_scan(
    const float* __restrict__ em_lin, const unsigned char* __restrict__ PT,
    const float* __restrict__ p, float* __restrict__ out)
{
    const int bb  = blockIdx.x;
    const int tid = threadIdx.x;
    const int w   = tid >> 6;
    const int l   = tid & 63;
    const int lc  = l & 15;
    const int lq  = l >> 4;

    __shared__ __align__(16) unsigned EwD[16 * 132];  // 16 rows x 528 B
    __shared__ float4 wm8[8];
    __shared__ float4 sgf;

    // ---- zero Ew (rows 4-15 stay zero forever) ----
    for (int i = tid; i < 16 * 132; i += 512) EwD[i] = 0u;

    // ---- B fragments (P, loaded once) ----
    v8i B[4][4];
#pragma unroll
    for (int nt = 0; nt < 4; ++nt) {
#pragma unroll
        for (int kt = 0; kt < 4; ++kt) {
            const uint4* src = (const uint4*)(PT + (size_t)((w * 4 + nt) * 16 + lc) * NS + kt * 128 + lq * 32);
            uint4 lo = src[0], hi = src[1];
            v8i bb8;
            bb8[0] = (int)lo.x; bb8[1] = (int)lo.y; bb8[2] = (int)lo.z; bb8[3] = (int)lo.w;
            bb8[4] = (int)hi.x; bb8[5] = (int)hi.y; bb8[6] = (int)hi.z; bb8[7] = (int)hi.w;
            B[nt][kt] = bb8;
        }
    }

    // ---- prior softmax denominator (all lanes) ----
    float zp = 0.f;
#pragma unroll
    for (int i = 0; i < 8; ++i) zp += __expf(p[l * 8 + i]);
    DPPADD(zp, 0x128); DPPADD(zp, 0x124); DPPADD(zp, 0xB1); DPPADD(zp, 0x4E);
    float Zp = __int_as_float(__builtin_amdgcn_readlane(__float_as_int(zp), 0))
             + __int_as_float(__builtin_amdgcn_readlane(__float_as_int(zp), 16))
             + __int_as_float(__builtin_amdgcn_readlane(__float_as_int(zp), 32))
             + __int_as_float(__builtin_amdgcn_readlane(__float_as_int(zp), 48));
    const float invZp = 1.0f / Zp;

    const int d0 = w * 64 + lc;          // state d for nt: d0 + 16*nt

    // ---- alpha_0 on lanes 0-15: av[nt][r], batch = bb*4+r ----
    float av[4][4];
    const float* ep[4];
    if (l < 16) {
#pragma unroll
        for (int r = 0; r < 4; ++r)
            ep[r] = em_lin + (size_t)(bb * 4 + r) * (NT * NS) + d0;
#pragma unroll
        for (int nt = 0; nt < 4; ++nt) {
            float pl = __expf(p[d0 + 16 * nt]) * invZp;
#pragma unroll
            for (int r = 0; r < 4; ++r)
                av[nt][r] = pl * ep[r][16 * nt];
        }
#pragma unroll
        for (int r = 0; r < 4; ++r) ep[r] += NS;
    }
    __syncthreads();   // Ew zero-init complete

    int gsum[4] = {18, 18, 18, 18};
    const unsigned sel1 = (l & 1) ? 0x07030501u : 0x02060004u;
    const unsigned sel2 = (l & 2) ? 0x07060302u : 0x01000504u;
    const uint4* eb4 = (const uint4*)&EwD[0];

    for (int t = 1; t < NT; ++t) {
        // ---- prefetch em(t) (consumed after the MFMA) ----
        float epf[4][4];
        if (l < 16) {
#pragma unroll
            for (int nt = 0; nt < 4; ++nt)
#pragma unroll
                for (int r = 0; r < 4; ++r)
                    epf[nt][r] = ep[r][16 * nt];
#pragma unroll
            for (int r = 0; r < 4; ++r) ep[r] += NS;
        }

        // ---- producer: per-wave per-batch max -> wm8[w] ----
        if (l < 16) {
            float m0 = fmaxf(fmaxf(av[0][0], av[1][0]), fmaxf(av[2][0], av[3][0]));
            float m1 = fmaxf(fmaxf(av[0][1], av[1][1]), fmaxf(av[2][1], av[3][1]));
            float m2 = fmaxf(fmaxf(av[0][2], av[1][2]), fmaxf(av[2][2], av[3][2]));
            float m3 = fmaxf(fmaxf(av[0][3], av[1][3]), fmaxf(av[2][3], av[3][3]));
            DPPMAX(m0, 0x128); DPPMAX(m0, 0x124); DPPMAX(m0, 0xB1); DPPMAX(m0, 0x4E);
            DPPMAX(m1, 0x128); DPPMAX(m1, 0x124); DPPMAX(m1, 0xB1); DPPMAX(m1, 0x4E);
            DPPMAX(m2, 0x128); DPPMAX(m2, 0x124); DPPMAX(m2, 0xB1); DPPMAX(m2, 0x4E);
            DPPMAX(m3, 0x128); DPPMAX(m3, 0x124); DPPMAX(m3, 0xB1); DPPMAX(m3, 0x4E);
            if (l == 0) wm8[w] = make_float4(m0, m1, m2, m3);
        }
        __syncthreads();                                   // B1

        if (l < 16) {
            // ---- cross-wave max (broadcast float4 reads) ----
            float4 m4 = wm8[0];
#pragma unroll
            for (int j = 1; j < 8; ++j) {
                float4 v = wm8[j];
                m4.x = fmaxf(m4.x, v.x); m4.y = fmaxf(m4.y, v.y);
                m4.z = fmaxf(m4.z, v.z); m4.w = fmaxf(m4.w, v.w);
            }
            float mb[4] = {m4.x, m4.y, m4.z, m4.w};
            float sc[4];
#pragma unroll
            for (int r = 0; r < 4; ++r) {
                unsigned ebx = __float_as_uint(mb[r]) >> 23;
                sc[r] = __uint_as_float((261u - ebx) << 23);   // 2^(134-eb)
                gsum[r] += (int)ebx - 126;
            }
            // ---- quantize + 4x4 byte transpose + Ew write ----
#pragma unroll
            for (int nt = 0; nt < 4; ++nt) {
                unsigned dw = pack4_e4m3(av[nt][0] * sc[0], av[nt][1] * sc[1],
                                         av[nt][2] * sc[2], av[nt][3] * sc[3]);
                int tmp = __builtin_amdgcn_mov_dpp((int)dw, 0xB1, 0xF, 0xF, true);
                dw = __builtin_amdgcn_perm(dw, (unsigned)tmp, sel1);
                tmp = __builtin_amdgcn_mov_dpp((int)dw, 0x4E, 0xF, 0xF, true);
                dw = __builtin_amdgcn_perm(dw, (unsigned)tmp, sel2);
                EwD[(l & 3) * 132 + w * 16 + nt * 4 + (lc >> 2)] = dw;
            }
        }
        __syncthreads();                                   // B2

        // ---- A fragments (row lc, k = kt*128 + lq*32, stride 33 uint4/row) ----
        v8i A[4];
#pragma unroll
        for (int kt = 0; kt < 4; ++kt) {
            uint4 lo = eb4[lc * 33 + kt * 8 + lq * 2];
            uint4 hi = eb4[lc * 33 + kt * 8 + lq * 2 + 1];
            v8i aa;
            aa[0] = (int)lo.x; aa[1] = (int)lo.y; aa[2] = (int)lo.z; aa[3] = (int)lo.w;
            aa[4] = (int)hi.x; aa[5] = (int)hi.y; aa[6] = (int)hi.z; aa[7] = (int)hi.w;
            A[kt] = aa;
        }

        // ---- MFMA: Y = E . P ----
        v4f C[4];
#pragma unroll
        for (int nt = 0; nt < 4; ++nt) { C[nt][0] = 0.f; C[nt][1] = 0.f; C[nt][2] = 0.f; C[nt][3] = 0.f; }
#pragma unroll
        for (int kt = 0; kt < 4; ++kt)
#pragma unroll
            for (int nt = 0; nt < 4; ++nt)
                C[nt] = __builtin_amdgcn_mfma_scale_f32_16x16x128_f8f6f4(
                            A[kt], B[nt][kt], C[nt], 0, 0, 0, 0x7F7F7F7F, 0, 0x7F7F7F7F);

        // ---- av = C * em(t) (lanes 0-15 hold the 4 real batch rows) ----
        if (l < 16) {
#pragma unroll
            for (int nt = 0; nt < 4; ++nt)
#pragma unroll
                for (int r = 0; r < 4; ++r)
                    av[nt][r] = C[nt][r] * epf[nt][r];
        }
    }

    // ---- final: per-batch logsumexp ----
    if (l < 16) {
        float s0 = (av[0][0] + av[1][0]) + (av[2][0] + av[3][0]);
        float s1 = (av[0][1] + av[1][1]) + (av[2][1] + av[3][1]);
        float s2 = (av[0][2] + av[1][2]) + (av[2][2] + av[3][2]);
        float s3 = (av[0][3] + av[1][3]) + (av[2][3] + av[3][3]);
        DPPADD(s0, 0x128); DPPADD(s0, 0x124); DPPADD(s0, 0xB1); DPPADD(s0, 0x4E);
        DPPADD(s1, 0x128); DPPADD(s1, 0x124); DPPADD(s1, 0xB1); DPPADD(s1, 0x4E);
        DPPADD(s2, 0x128); DPPADD(s2, 0x124); DPPADD(s2, 0xB1); DPPADD(s2, 0x4E);
        DPPADD(s3, 0x128); DPPADD(s3, 0x124); DPPADD(s3, 0xB1); DPPADD(s3, 0x4E);
        if (l == 0) wm8[w] = make_float4(s0, s1, s2, s3);
        if (tid == 0)
            sgf = make_float4((float)gsum[0], (float)gsum[1], (float)gsum[2], (float)gsum[3]);
    }
    __syncthreads();
    if (tid < 4) {
        float s8 = 0.f;
#pragma unroll
        for (int j = 0; j < 8; ++j) s8 += ((const float*)&wm8[j])[tid];
        float L2 = __log2f(s8) + ((const float*)&sgf)[tid];
        atomicAdd(out, -(0.693147180559945f / 16.0f) * L2);
    }
}

// ---------------------------------------------------------------------------
extern "C" void kernel_launch(void* const* d_in, const int* in_sizes, int n_in,
                              void* d_out, int out_size, void* d_ws, size_t ws_size,
                              hipStream_t stream)
{
    const int*   ids = (const int*)d_in[0];   // [16][128]
    const float* em  = (const float*)d_in[1]; // [512][32000]
    const float* tm  = (const float*)d_in[2]; // [512][512]
    const float* p   = (const float*)d_in[3]; // [512]
    float* out = (float*)d_out;

    float*          em_lin = (float*)d_ws;                                             // 4 MB
    unsigned char*  PT     = (unsigned char*)d_ws + ((size_t)4 << 20);                 // 256 KB
    float*          zscale = (float*)((unsigned char*)d_ws + ((size_t)4 << 20) + ((size_t)256 << 10)); // 2 KB
    float*          scaleZ = (float*)((unsigned char*)d_ws + ((size_t)4 << 20) + ((size_t)260 << 10)); // 2 KB

    hipMemsetAsync(d_out, 0, sizeof(float), stream);

    k_setup1<<<1024, 256, 0, stream>>>(em, tm, scaleZ, zscale);
    k_setup2<<<1088, 256, 0, stream>>>(em, tm, ids, scaleZ, zscale, em_lin, PT);
    k_scan<<<4, 512, 0, stream>>>(em_lin, PT, p, out);
}